// Round 1
// baseline (1123.221 us; speedup 1.0000x reference)
//
#include <hip/hip_runtime.h>
#include <cstdint>

// ---------------------------------------------------------------------------
// MaskedTransformerDecoderLayer on MI355X.
// All GEMMs: bf16-MFMA 128x128 tile (16x16x32), fp32 accumulate.
// D=1024, NHEAD=8, NQ=256, B=8, S=4096, FF=4096.
// ---------------------------------------------------------------------------

typedef __attribute__((ext_vector_type(8))) __bf16 bf16x8;
typedef __attribute__((ext_vector_type(4))) float f32x4;
typedef __attribute__((ext_vector_type(8))) unsigned short ushort8;
typedef __attribute__((ext_vector_type(4))) unsigned short ushort4v;

__device__ __forceinline__ unsigned short f2bf(float f) {
  return __builtin_bit_cast(unsigned short, (__bf16)f);
}

// ---------------- cast fp32 -> bf16 (8 elems/thread) ----------------
__global__ __launch_bounds__(256) void cast_bf16_kernel(const float* __restrict__ in,
                                                        unsigned short* __restrict__ out,
                                                        int n8) {
  int i = blockIdx.x * 256 + threadIdx.x;
  if (i >= n8) return;
  const float4* p = (const float4*)in + (size_t)i * 2;
  float4 a = p[0], b = p[1];
  ushort8 o;
  o[0] = f2bf(a.x); o[1] = f2bf(a.y); o[2] = f2bf(a.z); o[3] = f2bf(a.w);
  o[4] = f2bf(b.x); o[5] = f2bf(b.y); o[6] = f2bf(b.z); o[7] = f2bf(b.w);
  ((ushort8*)out)[i] = o;
}

// ---------------- LayerNorm over D=1024, bf16 out ----------------
__global__ __launch_bounds__(256) void ln_bf16_kernel(const float* __restrict__ x,
                                                      const float* __restrict__ g,
                                                      const float* __restrict__ b,
                                                      unsigned short* __restrict__ out) {
  int row = blockIdx.x, tid = threadIdx.x;
  const float4* xr = (const float4*)(x + (size_t)row * 1024);
  float4 v = xr[tid];
  float s = v.x + v.y + v.z + v.w;
  float sq = v.x * v.x + v.y * v.y + v.z * v.z + v.w * v.w;
#pragma unroll
  for (int o = 32; o > 0; o >>= 1) { s += __shfl_xor(s, o); sq += __shfl_xor(sq, o); }
  __shared__ float red[8];
  int wave = tid >> 6, lane = tid & 63;
  if (lane == 0) { red[wave] = s; red[4 + wave] = sq; }
  __syncthreads();
  float ts = red[0] + red[1] + red[2] + red[3];
  float tq = red[4] + red[5] + red[6] + red[7];
  float mean = ts * (1.f / 1024.f);
  float var = tq * (1.f / 1024.f) - mean * mean;
  float rstd = rsqrtf(var + 1e-5f);
  float4 gv = ((const float4*)g)[tid];
  float4 bv = ((const float4*)b)[tid];
  ushort4v o;
  o[0] = f2bf((v.x - mean) * rstd * gv.x + bv.x);
  o[1] = f2bf((v.y - mean) * rstd * gv.y + bv.y);
  o[2] = f2bf((v.z - mean) * rstd * gv.z + bv.z);
  o[3] = f2bf((v.w - mean) * rstd * gv.w + bv.w);
  ((ushort4v*)(out + (size_t)row * 1024))[tid] = o;
}

// ---------------- rowwise softmax, optional +log(mask+1e-6), bf16 out -------
template <bool MASK, int CNT>
__global__ __launch_bounds__(256) void softmax_bf16_kernel(const float* __restrict__ sc,
                                                           const float* __restrict__ pm,
                                                           unsigned short* __restrict__ out,
                                                           float scale) {
  const int L = CNT * 256;
  int row = blockIdx.x, tid = threadIdx.x;
  const float* sr = sc + (size_t)row * L;
  float vals[CNT];
  float mx = -1e30f;
#pragma unroll
  for (int i = 0; i < CNT; i++) {
    int idx = tid + (i << 8);
    float v = sr[idx] * scale;
    if (MASK) v += __logf(pm[(size_t)row * L + idx] + 1e-6f);
    vals[i] = v;
    mx = fmaxf(mx, v);
  }
#pragma unroll
  for (int o = 32; o > 0; o >>= 1) mx = fmaxf(mx, __shfl_xor(mx, o));
  __shared__ float red[8];
  int wave = tid >> 6, lane = tid & 63;
  if (lane == 0) red[wave] = mx;
  __syncthreads();
  mx = fmaxf(fmaxf(red[0], red[1]), fmaxf(red[2], red[3]));
  float sum = 0.f;
#pragma unroll
  for (int i = 0; i < CNT; i++) { vals[i] = __expf(vals[i] - mx); sum += vals[i]; }
#pragma unroll
  for (int o = 32; o > 0; o >>= 1) sum += __shfl_xor(sum, o);
  if (lane == 0) red[4 + wave] = sum;
  __syncthreads();
  float rs = 1.f / (red[4] + red[5] + red[6] + red[7]);
#pragma unroll
  for (int i = 0; i < CNT; i++)
    out[(size_t)row * L + tid + (i << 8)] = f2bf(vals[i] * rs);
}

// ---------------- batched bf16 transpose (32x32 tiles via LDS) ----------------
// out[z][i][j] = in[z][j][i]; i is the contiguous dim of the input row.
__global__ __launch_bounds__(256) void transpose_bf16_kernel(
    const unsigned short* __restrict__ in, unsigned short* __restrict__ out,
    long in_off, int in_rs, long in_hi, long in_lo, int zdiv,
    long out_off, int out_rs, long out_hi, long out_lo) {
  __shared__ unsigned short t[32][33];
  int z = blockIdx.z;
  int zh = z / zdiv, zl = z % zdiv;
  const unsigned short* ib = in + in_off + (long)zh * in_hi + (long)zl * in_lo;
  unsigned short* ob = out + out_off + (long)zh * out_hi + (long)zl * out_lo;
  int i0 = blockIdx.x * 32;
  int j0 = blockIdx.y * 32;
  int tx = threadIdx.x & 31, ty = threadIdx.x >> 5;
#pragma unroll
  for (int r = ty; r < 32; r += 8) t[r][tx] = ib[(long)(j0 + r) * in_rs + i0 + tx];
  __syncthreads();
#pragma unroll
  for (int r = ty; r < 32; r += 8) ob[(long)(i0 + r) * out_rs + j0 + tx] = t[tx][r];
}

// ---------------- batched NT GEMM: C[m,n] = sum_k A[m,k]*B[n,k] ----------------
// 128x128 tile, BK=32, 4 waves, each wave 4x4 mfma_f32_16x16x32_bf16.
// Batch z: base += (z/zdiv)*hi + (z%zdiv)*lo per operand.
// AF32: A operand is fp32 in global, converted to bf16 during LDS staging.
template <bool AF32, bool BIAS, int ACT, bool RES, bool OUTF, bool OUTB>
__global__ __launch_bounds__(256) void gemm_nt_kernel(
    const void* __restrict__ Av, long a_off, int lda, long a_hi, long a_lo,
    const unsigned short* __restrict__ B, long b_off, int ldb, long b_hi, long b_lo,
    const float* __restrict__ bias, const float* __restrict__ Res,
    float* __restrict__ Cf, long c_off, int ldc, long c_hi, long c_lo,
    unsigned short* __restrict__ Cb, long cb_off, int ldcb, long cb_hi, long cb_lo,
    int K, int zdiv) {
  __shared__ unsigned short As[128 * 32];
  __shared__ unsigned short Bs[128 * 32];
  int tid = threadIdx.x;
  int wave = tid >> 6, lane = tid & 63;
  int z = blockIdx.z, zh = z / zdiv, zl = z % zdiv;
  long m0 = (long)blockIdx.x * 128, n0 = (long)blockIdx.y * 128;

  const unsigned short* Bb = B + b_off + zh * b_hi + zl * b_lo + n0 * ldb;
  const unsigned short* Ab16 = nullptr;
  const float* Abf = nullptr;
  if constexpr (AF32)
    Abf = (const float*)Av + a_off + zh * a_hi + zl * a_lo + m0 * lda;
  else
    Ab16 = (const unsigned short*)Av + a_off + zh * a_hi + zl * a_lo + m0 * lda;

  int srow = lane >> 2;        // 0..15 within a 16-row staging group
  int scol = (lane & 3) * 8;   // 0,8,16,24 (bf16 elems)
  int wm = (wave >> 1) * 64, wn = (wave & 1) * 64;
  int fr = lane & 15;
  int ko = (lane >> 4) * 8;

  f32x4 acc[4][4] = {};

  for (int k0 = 0; k0 < K; k0 += 32) {
    __syncthreads();
    if constexpr (AF32) {
      // 256 threads stage 128x32 fp32 -> bf16 LDS
      int row = tid >> 1;
      int cs = (tid & 1) * 16;
      const float* ap = Abf + (long)row * lda + k0 + cs;
      float4 f0 = ((const float4*)ap)[0];
      float4 f1 = ((const float4*)ap)[1];
      float4 f2 = ((const float4*)ap)[2];
      float4 f3 = ((const float4*)ap)[3];
      ushort8 u0, u1;
      u0[0] = f2bf(f0.x); u0[1] = f2bf(f0.y); u0[2] = f2bf(f0.z); u0[3] = f2bf(f0.w);
      u0[4] = f2bf(f1.x); u0[5] = f2bf(f1.y); u0[6] = f2bf(f1.z); u0[7] = f2bf(f1.w);
      u1[0] = f2bf(f2.x); u1[1] = f2bf(f2.y); u1[2] = f2bf(f2.z); u1[3] = f2bf(f2.w);
      u1[4] = f2bf(f3.x); u1[5] = f2bf(f3.y); u1[6] = f2bf(f3.z); u1[7] = f2bf(f3.w);
      ushort8* dst = (ushort8*)(As + row * 32 + cs);
      dst[0] = u0;
      dst[1] = u1;
    } else {
#pragma unroll
      for (int is = 0; is < 2; is++) {
        int rbase = wave * 32 + is * 16;
        const unsigned short* g = Ab16 + (long)(rbase + srow) * lda + k0 + scol;
        __builtin_amdgcn_global_load_lds(
            (const __attribute__((address_space(1))) unsigned int*)g,
            (__attribute__((address_space(3))) unsigned int*)(As + rbase * 32), 16, 0, 0);
      }
    }
#pragma unroll
    for (int is = 0; is < 2; is++) {
      int rbase = wave * 32 + is * 16;
      const unsigned short* g = Bb + (long)(rbase + srow) * ldb + k0 + scol;
      __builtin_amdgcn_global_load_lds(
          (const __attribute__((address_space(1))) unsigned int*)g,
          (__attribute__((address_space(3))) unsigned int*)(Bs + rbase * 32), 16, 0, 0);
    }
    __syncthreads();

    bf16x8 af[4], bfv[4];
#pragma unroll
    for (int i = 0; i < 4; i++)
      af[i] = *(const bf16x8*)(As + (wm + i * 16 + fr) * 32 + ko);
#pragma unroll
    for (int j = 0; j < 4; j++)
      bfv[j] = *(const bf16x8*)(Bs + (wn + j * 16 + fr) * 32 + ko);
#pragma unroll
    for (int i = 0; i < 4; i++)
#pragma unroll
      for (int j = 0; j < 4; j++)
        acc[i][j] = __builtin_amdgcn_mfma_f32_16x16x32_bf16(af[i], bfv[j], acc[i][j], 0, 0, 0);
  }

  // epilogue: C/D layout col=lane&15, row=(lane>>4)*4+r
  long cfo = c_off + zh * c_hi + zl * c_lo;
  long cbo = cb_off + zh * cb_hi + zl * cb_lo;
  int rq = (lane >> 4) * 4;
#pragma unroll
  for (int i = 0; i < 4; i++) {
    long rbase = m0 + wm + i * 16 + rq;
#pragma unroll
    for (int j = 0; j < 4; j++) {
      long cc = n0 + wn + j * 16 + fr;
      float bsv = BIAS ? bias[cc] : 0.f;
#pragma unroll
      for (int r = 0; r < 4; r++) {
        float v = acc[i][j][r] + bsv;
        long ro = rbase + r;
        if constexpr (RES) v += Res[cfo + ro * ldc + cc];
        if constexpr (ACT == 1) v = 0.5f * v * (1.f + erff(v * 0.7071067811865475f));
        if constexpr (ACT == 2) v = 1.f / (1.f + __expf(-v));
        if constexpr (OUTF) Cf[cfo + ro * ldc + cc] = v;
        if constexpr (OUTB) Cb[cbo + ro * ldcb + cc] = f2bf(v);
      }
    }
  }
}

// ---------------------------------------------------------------------------
// Host side
// ---------------------------------------------------------------------------
template <bool AF32, bool BIAS, int ACT, bool RES, bool OUTF, bool OUTB>
static void launch_gemm(hipStream_t s, int M, int N, int K, int nz, int zdiv,
                        const void* A, long a_off, int lda, long a_hi, long a_lo,
                        const unsigned short* B, long b_off, int ldb, long b_hi, long b_lo,
                        const float* bias, const float* Res,
                        float* Cf, long c_off, int ldc, long c_hi, long c_lo,
                        unsigned short* Cb, long cb_off, int ldcb, long cb_hi, long cb_lo) {
  dim3 g(M / 128, N / 128, nz);
  gemm_nt_kernel<AF32, BIAS, ACT, RES, OUTF, OUTB><<<g, dim3(256), 0, s>>>(
      A, a_off, lda, a_hi, a_lo, B, b_off, ldb, b_hi, b_lo, bias, Res,
      Cf, c_off, ldc, c_hi, c_lo, Cb, cb_off, ldcb, cb_hi, cb_lo, K, zdiv);
}

// workspace layout (bytes); aliased regions documented inline. peak = 240 MB
static const long WB_SAIN = 0;          // 6 MB  bf16 sa_in_w
static const long WB_SAOUT = 6291456;   // 2 MB
static const long WB_WQ = 8388608;      // 2 MB
static const long WB_WK = 10485760;     // 2 MB
static const long WB_WV = 12582912;     // 2 MB
static const long WB_WO = 14680064;     // 2 MB
static const long WB_W1 = 16777216;     // 8 MB
static const long WB_W2 = 25165824;     // 8 MB
static const long WB_MW = 33554432;     // 8 MB
static const long OF_K = 41943040;      // 64 MB: K proj; later V^T
static const long OF_V = 109051904;     // 64 MB: V proj
static const long OF_QKV = 176160768;   // 12 MB: qkv; later x1 (fp32, 8 MB)
static const long OF_SC = 188743680;    // 32 MB: self-sc / cross-sc / x2 (fp32)
static const long OF_P = 222298112;     // 16 MB: attn_p / attn2 / h (bf16)
static const long OF_QN = 239075328;    // 4 MB: LN outs / self V^T (time-disjoint)
static const long OF_Q = 243269632;     // 4 MB: Q proj
static const long OF_CTX = 247463936;   // 4 MB: ctx / ctx2 / x3_bf

extern "C" void kernel_launch(void* const* d_in, const int* in_sizes, int n_in,
                              void* d_out, int out_size, void* d_ws, size_t ws_size,
                              hipStream_t stream) {
  (void)in_sizes; (void)n_in; (void)out_size; (void)ws_size;
  const float* query = (const float*)d_in[0];
  const float* memoryp = (const float*)d_in[1];
  const float* prev_mask = (const float*)d_in[2];
  const float* sa_in_w = (const float*)d_in[5];
  const float* sa_in_b = (const float*)d_in[6];
  const float* sa_out_w = (const float*)d_in[7];
  const float* sa_out_b = (const float*)d_in[8];
  const float* ln1_g = (const float*)d_in[9], * ln1_b = (const float*)d_in[10];
  const float* ln2_g = (const float*)d_in[11], * ln2_b = (const float*)d_in[12];
  const float* ln3_g = (const float*)d_in[13], * ln3_b = (const float*)d_in[14];
  const float* wq = (const float*)d_in[15], * bq = (const float*)d_in[16];
  const float* wk = (const float*)d_in[17], * bk = (const float*)d_in[18];
  const float* wv = (const float*)d_in[19], * bv = (const float*)d_in[20];
  const float* wo = (const float*)d_in[21], * bo = (const float*)d_in[22];
  const float* w1 = (const float*)d_in[23], * b1 = (const float*)d_in[24];
  const float* w2 = (const float*)d_in[25], * b2 = (const float*)d_in[26];
  const float* mask_w = (const float*)d_in[27], * mask_b = (const float*)d_in[28];

  uint8_t* ws = (uint8_t*)d_ws;
  auto bf = [&](long off) { return (unsigned short*)(ws + off); };
  auto fp = [&](long off) { return (float*)(ws + off); };
  unsigned short* ZB = nullptr;
  float* ZF = nullptr;

  auto cast = [&](const float* src, long dst, int n) {
    int n8 = n / 8;
    cast_bf16_kernel<<<dim3((n8 + 255) / 256), dim3(256), 0, stream>>>(src, bf(dst), n8);
  };

  // weights -> bf16
  cast(sa_in_w, WB_SAIN, 3072 * 1024);
  cast(sa_out_w, WB_SAOUT, 1024 * 1024);
  cast(wq, WB_WQ, 1024 * 1024);
  cast(wk, WB_WK, 1024 * 1024);
  cast(wv, WB_WV, 1024 * 1024);
  cast(wo, WB_WO, 1024 * 1024);
  cast(w1, WB_W1, 4096 * 1024);
  cast(w2, WB_W2, 1024 * 4096);
  cast(mask_w, WB_MW, 4096 * 1024);

  // ---- self attention ----
  ln_bf16_kernel<<<2048, 256, 0, stream>>>(query, ln1_g, ln1_b, bf(OF_QN));

  // qkv = qn @ sa_in_w^T + b  -> bf16 [2048 x 3072]
  launch_gemm<false, true, 0, false, false, true>(stream, 2048, 3072, 1024, 1, 1,
      bf(OF_QN), 0, 1024, 0, 0, bf(WB_SAIN), 0, 1024, 0, 0, sa_in_b, nullptr,
      ZF, 0, 0, 0, 0, bf(OF_QKV), 0, 3072, 0, 0);

  // self scores [b,h][256][256] fp32; z=(b*8+h)
  launch_gemm<false, false, 0, false, true, false>(stream, 256, 256, 128, 64, 8,
      bf(OF_QKV), 0, 24576, 3072, 128,
      bf(OF_QKV), 1024, 24576, 3072, 128, nullptr, nullptr,
      fp(OF_SC), 0, 256, 524288, 65536, ZB, 0, 0, 0, 0);

  softmax_bf16_kernel<false, 1><<<16384, 256, 0, stream>>>(
      fp(OF_SC), nullptr, bf(OF_P), 0.08838834764831845f);

  // self V^T: VT_s[z=(b*8+h)][d=128][s=256] from qkv v-slice
  transpose_bf16_kernel<<<dim3(4, 8, 64), 256, 0, stream>>>(
      bf(OF_QKV), bf(OF_QN), 2048L, 24576, 3072L, 128L, 8, 0L, 256, 262144L, 32768L);

  // ctx[(q*8+b)*1024 + h*128 + d] = attn_p @ VT_s^T
  launch_gemm<false, false, 0, false, false, true>(stream, 256, 128, 256, 64, 8,
      bf(OF_P), 0, 256, 524288, 65536,
      bf(OF_QN), 0, 256, 262144, 32768, nullptr, nullptr,
      ZF, 0, 0, 0, 0, bf(OF_CTX), 0, 8192, 1024, 128);

  // x1 = query + ctx @ sa_out_w^T + b -> fp32 at OF_QKV
  launch_gemm<false, true, 0, true, true, false>(stream, 2048, 1024, 1024, 1, 1,
      bf(OF_CTX), 0, 1024, 0, 0, bf(WB_SAOUT), 0, 1024, 0, 0, sa_out_b, query,
      fp(OF_QKV), 0, 1024, 0, 0, ZB, 0, 0, 0, 0);

  // ---- cross attention ----
  ln_bf16_kernel<<<2048, 256, 0, stream>>>(fp(OF_QKV), ln2_g, ln2_b, bf(OF_QN));

  launch_gemm<false, true, 0, false, false, true>(stream, 2048, 1024, 1024, 1, 1,
      bf(OF_QN), 0, 1024, 0, 0, bf(WB_WQ), 0, 1024, 0, 0, bq, nullptr,
      ZF, 0, 0, 0, 0, bf(OF_Q), 0, 1024, 0, 0);

  // K,V projections from fp32 memory (convert during staging)
  launch_gemm<true, true, 0, false, false, true>(stream, 32768, 1024, 1024, 1, 1,
      memoryp, 0, 1024, 0, 0, bf(WB_WK), 0, 1024, 0, 0, bk, nullptr,
      ZF, 0, 0, 0, 0, bf(OF_K), 0, 1024, 0, 0);
  launch_gemm<true, true, 0, false, false, true>(stream, 32768, 1024, 1024, 1, 1,
      memoryp, 0, 1024, 0, 0, bf(WB_WV), 0, 1024, 0, 0, bv, nullptr,
      ZF, 0, 0, 0, 0, bf(OF_V), 0, 1024, 0, 0);

  // cross scores [b][256][4096] fp32
  launch_gemm<false, false, 0, false, true, false>(stream, 256, 4096, 1024, 8, 1,
      bf(OF_Q), 0, 8192, 1024, 0,
      bf(OF_K), 0, 8192, 1024, 0, nullptr, nullptr,
      fp(OF_SC), 0, 4096, 1048576, 0, ZB, 0, 0, 0, 0);

  softmax_bf16_kernel<true, 16><<<2048, 256, 0, stream>>>(
      fp(OF_SC), prev_mask, bf(OF_P), 0.03125f);

  // V^T[b][d=1024][s=4096] into OF_K region (K proj is dead now)
  transpose_bf16_kernel<<<dim3(32, 128, 8), 256, 0, stream>>>(
      bf(OF_V), bf(OF_K), 0L, 8192, 1024L, 0L, 1, 0L, 4096, 4194304L, 0L);

  // ctx2[(q*8+b)*1024 + d] = attn2 @ VT^T
  launch_gemm<false, false, 0, false, false, true>(stream, 256, 1024, 4096, 8, 1,
      bf(OF_P), 0, 4096, 1048576, 0,
      bf(OF_K), 0, 4096, 4194304, 0, nullptr, nullptr,
      ZF, 0, 0, 0, 0, bf(OF_CTX), 0, 8192, 1024, 0);

  // x2 = x1 + ctx2 @ wo^T + bo -> fp32 at OF_SC
  launch_gemm<false, true, 0, true, true, false>(stream, 2048, 1024, 1024, 1, 1,
      bf(OF_CTX), 0, 1024, 0, 0, bf(WB_WO), 0, 1024, 0, 0, bo, fp(OF_QKV),
      fp(OF_SC), 0, 1024, 0, 0, ZB, 0, 0, 0, 0);

  // ---- FFN ----
  ln_bf16_kernel<<<2048, 256, 0, stream>>>(fp(OF_SC), ln3_g, ln3_b, bf(OF_QN));

  // h = gelu(qn3 @ w1^T + b1) -> bf16 [2048 x 4096]
  launch_gemm<false, true, 1, false, false, true>(stream, 2048, 4096, 1024, 1, 1,
      bf(OF_QN), 0, 1024, 0, 0, bf(WB_W1), 0, 1024, 0, 0, b1, nullptr,
      ZF, 0, 0, 0, 0, bf(OF_P), 0, 4096, 0, 0);

  // x3 = x2 + h @ w2^T + b2 -> d_out (fp32) and bf16 copy for mask head
  launch_gemm<false, true, 0, true, true, true>(stream, 2048, 1024, 4096, 1, 1,
      bf(OF_P), 0, 4096, 0, 0, bf(WB_W2), 0, 4096, 0, 0, b2, fp(OF_SC),
      (float*)d_out, 0, 1024, 0, 0, bf(OF_CTX), 0, 1024, 0, 0);

  // pred_mask[b][q][4096] = sigmoid(x3 @ mask_w^T + mask_b)
  launch_gemm<false, true, 2, false, true, false>(stream, 256, 4096, 1024, 8, 1,
      bf(OF_CTX), 0, 8192, 1024, 0,
      bf(WB_MW), 0, 1024, 0, 0, mask_b, nullptr,
      (float*)d_out + 2097152, 0, 4096, 1048576, 0, ZB, 0, 0, 0, 0);
}

// Round 2
// 1033.846 us; speedup vs baseline: 1.0864x; 1.0864x over previous
//
#include <hip/hip_runtime.h>
#include <cstdint>

// ---------------------------------------------------------------------------
// MaskedTransformerDecoderLayer on MI355X.
// All GEMMs: bf16-MFMA tiles (16x16x32), fp32 accumulate.
// D=1024, NHEAD=8, NQ=256, B=8, S=4096, FF=4096.
// ---------------------------------------------------------------------------

typedef __attribute__((ext_vector_type(8))) __bf16 bf16x8;
typedef __attribute__((ext_vector_type(4))) float f32x4;
typedef __attribute__((ext_vector_type(8))) unsigned short ushort8;
typedef __attribute__((ext_vector_type(4))) unsigned short ushort4v;

__device__ __forceinline__ unsigned short f2bf(float f) {
  return __builtin_bit_cast(unsigned short, (__bf16)f);
}

// ---------------- cast fp32 -> bf16 (8 elems/thread) ----------------
__global__ __launch_bounds__(256) void cast_bf16_kernel(const float* __restrict__ in,
                                                        unsigned short* __restrict__ out,
                                                        int n8) {
  int i = blockIdx.x * 256 + threadIdx.x;
  if (i >= n8) return;
  const float4* p = (const float4*)in + (size_t)i * 2;
  float4 a = p[0], b = p[1];
  ushort8 o;
  o[0] = f2bf(a.x); o[1] = f2bf(a.y); o[2] = f2bf(a.z); o[3] = f2bf(a.w);
  o[4] = f2bf(b.x); o[5] = f2bf(b.y); o[6] = f2bf(b.z); o[7] = f2bf(b.w);
  ((ushort8*)out)[i] = o;
}

// ---------------- fused multi-tensor cast (dst regions contiguous) ----------
struct CastSegs {
  const float* src[9];
  int cum[10];  // cumulative n8 counts
};
__global__ __launch_bounds__(256) void cast_multi_kernel(CastSegs cs,
                                                         unsigned short* __restrict__ out) {
  int i = blockIdx.x * 256 + threadIdx.x;
  if (i >= cs.cum[9]) return;
  int s = 0;
  while (i >= cs.cum[s + 1]) s++;
  const float4* p = (const float4*)cs.src[s] + (size_t)(i - cs.cum[s]) * 2;
  float4 a = p[0], b = p[1];
  ushort8 o;
  o[0] = f2bf(a.x); o[1] = f2bf(a.y); o[2] = f2bf(a.z); o[3] = f2bf(a.w);
  o[4] = f2bf(b.x); o[5] = f2bf(b.y); o[6] = f2bf(b.z); o[7] = f2bf(b.w);
  ((ushort8*)out)[i] = o;
}

__global__ __launch_bounds__(256) void bias_concat_kernel(const float* __restrict__ a,
                                                          const float* __restrict__ b,
                                                          float* __restrict__ o) {
  int i = blockIdx.x * 256 + threadIdx.x;
  o[i] = i < 1024 ? a[i] : b[i - 1024];
}

// ---------------- LayerNorm over D=1024, bf16 out ----------------
__global__ __launch_bounds__(256) void ln_bf16_kernel(const float* __restrict__ x,
                                                      const float* __restrict__ g,
                                                      const float* __restrict__ b,
                                                      unsigned short* __restrict__ out) {
  int row = blockIdx.x, tid = threadIdx.x;
  const float4* xr = (const float4*)(x + (size_t)row * 1024);
  float4 v = xr[tid];
  float s = v.x + v.y + v.z + v.w;
  float sq = v.x * v.x + v.y * v.y + v.z * v.z + v.w * v.w;
#pragma unroll
  for (int o = 32; o > 0; o >>= 1) { s += __shfl_xor(s, o); sq += __shfl_xor(sq, o); }
  __shared__ float red[8];
  int wave = tid >> 6, lane = tid & 63;
  if (lane == 0) { red[wave] = s; red[4 + wave] = sq; }
  __syncthreads();
  float ts = red[0] + red[1] + red[2] + red[3];
  float tq = red[4] + red[5] + red[6] + red[7];
  float mean = ts * (1.f / 1024.f);
  float var = tq * (1.f / 1024.f) - mean * mean;
  float rstd = rsqrtf(var + 1e-5f);
  float4 gv = ((const float4*)g)[tid];
  float4 bv = ((const float4*)b)[tid];
  ushort4v o;
  o[0] = f2bf((v.x - mean) * rstd * gv.x + bv.x);
  o[1] = f2bf((v.y - mean) * rstd * gv.y + bv.y);
  o[2] = f2bf((v.z - mean) * rstd * gv.z + bv.z);
  o[3] = f2bf((v.w - mean) * rstd * gv.w + bv.w);
  ((ushort4v*)(out + (size_t)row * 1024))[tid] = o;
}

// ---------------- rowwise softmax, optional +log(mask+1e-6), bf16 out -------
template <bool MASK, int CNT>
__global__ __launch_bounds__(256) void softmax_bf16_kernel(const float* __restrict__ sc,
                                                           const float* __restrict__ pm,
                                                           unsigned short* __restrict__ out,
                                                           float scale) {
  const int L = CNT * 256;
  int row = blockIdx.x, tid = threadIdx.x;
  const float* sr = sc + (size_t)row * L;
  float vals[CNT];
  float mx = -1e30f;
#pragma unroll
  for (int i = 0; i < CNT; i++) {
    int idx = tid + (i << 8);
    float v = sr[idx] * scale;
    if (MASK) v += __logf(pm[(size_t)row * L + idx] + 1e-6f);
    vals[i] = v;
    mx = fmaxf(mx, v);
  }
#pragma unroll
  for (int o = 32; o > 0; o >>= 1) mx = fmaxf(mx, __shfl_xor(mx, o));
  __shared__ float red[8];
  int wave = tid >> 6, lane = tid & 63;
  if (lane == 0) red[wave] = mx;
  __syncthreads();
  mx = fmaxf(fmaxf(red[0], red[1]), fmaxf(red[2], red[3]));
  float sum = 0.f;
#pragma unroll
  for (int i = 0; i < CNT; i++) { vals[i] = __expf(vals[i] - mx); sum += vals[i]; }
#pragma unroll
  for (int o = 32; o > 0; o >>= 1) sum += __shfl_xor(sum, o);
  if (lane == 0) red[4 + wave] = sum;
  __syncthreads();
  float rs = 1.f / (red[4] + red[5] + red[6] + red[7]);
#pragma unroll
  for (int i = 0; i < CNT; i++)
    out[(size_t)row * L + tid + (i << 8)] = f2bf(vals[i] * rs);
}

// ---------------- batched bf16 transpose (32x32 tiles via LDS) ----------------
__global__ __launch_bounds__(256) void transpose_bf16_kernel(
    const unsigned short* __restrict__ in, unsigned short* __restrict__ out,
    long in_off, int in_rs, long in_hi, long in_lo, int zdiv,
    long out_off, int out_rs, long out_hi, long out_lo) {
  __shared__ unsigned short t[32][33];
  int z = blockIdx.z;
  int zh = z / zdiv, zl = z % zdiv;
  const unsigned short* ib = in + in_off + (long)zh * in_hi + (long)zl * in_lo;
  unsigned short* ob = out + out_off + (long)zh * out_hi + (long)zl * out_lo;
  int i0 = blockIdx.x * 32;
  int j0 = blockIdx.y * 32;
  int tx = threadIdx.x & 31, ty = threadIdx.x >> 5;
#pragma unroll
  for (int r = ty; r < 32; r += 8) t[r][tx] = ib[(long)(j0 + r) * in_rs + i0 + tx];
  __syncthreads();
#pragma unroll
  for (int r = ty; r < 32; r += 8) ob[(long)(i0 + r) * out_rs + j0 + tx] = t[tx][r];
}

// ---------------- batched NT GEMM: C[m,n] = sum_k A[m,k]*B[n,k] ----------------
// Tile TM x 128, BK=32, 4 waves (2x2). TM=128: per-wave 64x64 (acc 4x4).
// TM=64: per-wave 32x64 (acc 2x4). AF32: A is fp32, converted during staging
// (TM=128 only). KVSPLIT: bf16 output cols [0,1024) -> plane 0, [1024,2048) ->
// plane 1 at +cb_hi elems (planar K/V from fused projection).
template <int TM, bool AF32, bool BIAS, int ACT, bool RES, bool OUTF, bool OUTB, bool KVSPLIT>
__global__ __launch_bounds__(256) void gemm_nt_kernel(
    const void* __restrict__ Av, long a_off, int lda, long a_hi, long a_lo,
    const unsigned short* __restrict__ B, long b_off, int ldb, long b_hi, long b_lo,
    const float* __restrict__ bias, const float* __restrict__ Res,
    float* __restrict__ Cf, long c_off, int ldc, long c_hi, long c_lo,
    unsigned short* __restrict__ Cb, long cb_off, int ldcb, long cb_hi, long cb_lo,
    int K, int zdiv) {
  constexpr int MI = TM / 32;
  __shared__ unsigned short As[TM * 32];
  __shared__ unsigned short Bs[128 * 32];
  int tid = threadIdx.x;
  int wave = tid >> 6, lane = tid & 63;
  int z = blockIdx.z, zh = z / zdiv, zl = z % zdiv;
  long m0 = (long)blockIdx.x * TM, n0 = (long)blockIdx.y * 128;

  const unsigned short* Bb = B + b_off + zh * b_hi + zl * b_lo + n0 * ldb;
  const unsigned short* Ab16 = nullptr;
  const float* Abf = nullptr;
  if constexpr (AF32)
    Abf = (const float*)Av + a_off + zh * a_hi + zl * a_lo + m0 * lda;
  else
    Ab16 = (const unsigned short*)Av + a_off + zh * a_hi + zl * a_lo + m0 * lda;

  int srow = lane >> 2;
  int scol = (lane & 3) * 8;
  int wm = (wave >> 1) * (TM / 2), wn = (wave & 1) * 64;
  int fr = lane & 15;
  int ko = (lane >> 4) * 8;

  f32x4 acc[MI][4] = {};

  for (int k0 = 0; k0 < K; k0 += 32) {
    __syncthreads();
    if constexpr (AF32) {
      // 256 threads stage 128x32 fp32 -> bf16 LDS (TM=128 only)
      int row = tid >> 1;
      int cs = (tid & 1) * 16;
      const float* ap = Abf + (long)row * lda + k0 + cs;
      float4 f0 = ((const float4*)ap)[0];
      float4 f1 = ((const float4*)ap)[1];
      float4 f2 = ((const float4*)ap)[2];
      float4 f3 = ((const float4*)ap)[3];
      ushort8 u0, u1;
      u0[0] = f2bf(f0.x); u0[1] = f2bf(f0.y); u0[2] = f2bf(f0.z); u0[3] = f2bf(f0.w);
      u0[4] = f2bf(f1.x); u0[5] = f2bf(f1.y); u0[6] = f2bf(f1.z); u0[7] = f2bf(f1.w);
      u1[0] = f2bf(f2.x); u1[1] = f2bf(f2.y); u1[2] = f2bf(f2.z); u1[3] = f2bf(f2.w);
      u1[4] = f2bf(f3.x); u1[5] = f2bf(f3.y); u1[6] = f2bf(f3.z); u1[7] = f2bf(f3.w);
      ushort8* dst = (ushort8*)(As + row * 32 + cs);
      dst[0] = u0;
      dst[1] = u1;
    } else {
#pragma unroll
      for (int is = 0; is < TM / 64; is++) {
        int rbase = wave * (TM / 4) + is * 16;
        const unsigned short* g = Ab16 + (long)(rbase + srow) * lda + k0 + scol;
        __builtin_amdgcn_global_load_lds(
            (const __attribute__((address_space(1))) unsigned int*)g,
            (__attribute__((address_space(3))) unsigned int*)(As + rbase * 32), 16, 0, 0);
      }
    }
#pragma unroll
    for (int is = 0; is < 2; is++) {
      int rbase = wave * 32 + is * 16;
      const unsigned short* g = Bb + (long)(rbase + srow) * ldb + k0 + scol;
      __builtin_amdgcn_global_load_lds(
          (const __attribute__((address_space(1))) unsigned int*)g,
          (__attribute__((address_space(3))) unsigned int*)(Bs + rbase * 32), 16, 0, 0);
    }
    __syncthreads();

    bf16x8 af[MI], bfv[4];
#pragma unroll
    for (int i = 0; i < MI; i++)
      af[i] = *(const bf16x8*)(As + (wm + i * 16 + fr) * 32 + ko);
#pragma unroll
    for (int j = 0; j < 4; j++)
      bfv[j] = *(const bf16x8*)(Bs + (wn + j * 16 + fr) * 32 + ko);
#pragma unroll
    for (int i = 0; i < MI; i++)
#pragma unroll
      for (int j = 0; j < 4; j++)
        acc[i][j] = __builtin_amdgcn_mfma_f32_16x16x32_bf16(af[i], bfv[j], acc[i][j], 0, 0, 0);
  }

  // epilogue: C/D layout col=lane&15, row=(lane>>4)*4+r
  long cfo = c_off + zh * c_hi + zl * c_lo;
  long cbo = cb_off + zh * cb_hi + zl * cb_lo;
  int rq = (lane >> 4) * 4;
#pragma unroll
  for (int i = 0; i < MI; i++) {
    long rbase = m0 + wm + i * 16 + rq;
#pragma unroll
    for (int j = 0; j < 4; j++) {
      long cc = n0 + wn + j * 16 + fr;
      float bsv = BIAS ? bias[cc] : 0.f;
#pragma unroll
      for (int r = 0; r < 4; r++) {
        float v = acc[i][j][r] + bsv;
        long ro = rbase + r;
        if constexpr (RES) v += Res[cfo + ro * ldc + cc];
        if constexpr (ACT == 1) v = 0.5f * v * (1.f + erff(v * 0.7071067811865475f));
        if constexpr (ACT == 2) v = 1.f / (1.f + __expf(-v));
        if constexpr (OUTF) Cf[cfo + ro * ldc + cc] = v;
        if constexpr (OUTB) {
          long p = KVSPLIT ? ((cc >> 10) * cb_hi + (cc & 1023)) : cc;
          Cb[cbo + ro * ldcb + p] = f2bf(v);
        }
      }
    }
  }
}

// ---------------------------------------------------------------------------
// Host side
// ---------------------------------------------------------------------------
template <int TM, bool AF32, bool BIAS, int ACT, bool RES, bool OUTF, bool OUTB, bool KVSPLIT = false>
static void launch_gemm(hipStream_t s, int M, int N, int K, int nz, int zdiv,
                        const void* A, long a_off, int lda, long a_hi, long a_lo,
                        const unsigned short* B, long b_off, int ldb, long b_hi, long b_lo,
                        const float* bias, const float* Res,
                        float* Cf, long c_off, int ldc, long c_hi, long c_lo,
                        unsigned short* Cb, long cb_off, int ldcb, long cb_hi, long cb_lo) {
  dim3 g(M / TM, N / 128, nz);
  gemm_nt_kernel<TM, AF32, BIAS, ACT, RES, OUTF, OUTB, KVSPLIT><<<g, dim3(256), 0, s>>>(
      A, a_off, lda, a_hi, a_lo, B, b_off, ldb, b_hi, b_lo, bias, Res,
      Cf, c_off, ldc, c_hi, c_lo, Cb, cb_off, ldcb, cb_hi, cb_lo, K, zdiv);
}

// workspace layout (bytes). Weight regions 0..40MiB are CONTIGUOUS in cast order.
static const long WB_SAIN = 0;          // 6 MiB
static const long WB_SAOUT = 6291456;   // 2 MiB
static const long WB_WQ = 8388608;      // 2 MiB
static const long WB_WK = 10485760;     // 2 MiB  (wk||wv contiguous -> fused KV B)
static const long WB_WV = 12582912;     // 2 MiB
static const long WB_WO = 14680064;     // 2 MiB
static const long WB_W1 = 16777216;     // 8 MiB
static const long WB_W2 = 25165824;     // 8 MiB
static const long WB_MW = 33554432;     // 8 MiB
static const long OF_K = 41943040;      // 64 MiB: K planar; later V^T
static const long OF_V = 109051904;     // 64 MiB: V planar
static const long OF_QKV = 176160768;   // 12 MiB: qkv bf16; later x1 (fp32, 8 MiB)
static const long OF_BKV = 187695104;   // 8 KiB: concat [bk;bv] (within QKV region, past x1)
static const long OF_SC = 188743680;    // 32 MiB: self-sc / cross-sc / x2 (fp32)
static const long OF_P = 222298112;     // 16 MiB: attn_p / attn2 / h (bf16)
static const long OF_QN = 239075328;    // 4 MiB: LN outs / self V^T (time-disjoint)
static const long OF_Q = 243269632;     // 4 MiB: Q proj
static const long OF_CTX = 247463936;   // 4 MiB: ctx / ctx2 / x3_bf  (end 251658240)
static const long OF_MEMBF = 251658240; // 64 MiB: memory cast to bf16 (fast path only)
static const size_t FAST_WS = 318767104;

extern "C" void kernel_launch(void* const* d_in, const int* in_sizes, int n_in,
                              void* d_out, int out_size, void* d_ws, size_t ws_size,
                              hipStream_t stream) {
  (void)in_sizes; (void)n_in; (void)out_size;
  const float* query = (const float*)d_in[0];
  const float* memoryp = (const float*)d_in[1];
  const float* prev_mask = (const float*)d_in[2];
  const float* sa_in_w = (const float*)d_in[5];
  const float* sa_in_b = (const float*)d_in[6];
  const float* sa_out_w = (const float*)d_in[7];
  const float* sa_out_b = (const float*)d_in[8];
  const float* ln1_g = (const float*)d_in[9], * ln1_b = (const float*)d_in[10];
  const float* ln2_g = (const float*)d_in[11], * ln2_b = (const float*)d_in[12];
  const float* ln3_g = (const float*)d_in[13], * ln3_b = (const float*)d_in[14];
  const float* wq = (const float*)d_in[15], * bq = (const float*)d_in[16];
  const float* wk = (const float*)d_in[17], * bk = (const float*)d_in[18];
  const float* wv = (const float*)d_in[19], * bv = (const float*)d_in[20];
  const float* wo = (const float*)d_in[21], * bo = (const float*)d_in[22];
  const float* w1 = (const float*)d_in[23], * b1 = (const float*)d_in[24];
  const float* w2 = (const float*)d_in[25], * b2 = (const float*)d_in[26];
  const float* mask_w = (const float*)d_in[27], * mask_b = (const float*)d_in[28];

  uint8_t* ws = (uint8_t*)d_ws;
  auto bf = [&](long off) { return (unsigned short*)(ws + off); };
  auto fp = [&](long off) { return (float*)(ws + off); };
  unsigned short* ZB = nullptr;
  float* ZF = nullptr;
  const bool fast = ws_size >= FAST_WS;

  // ---- all 9 weight casts in one launch (dst = ws[0..40MiB) contiguous) ----
  {
    CastSegs cs;
    const float* srcs[9] = {sa_in_w, sa_out_w, wq, wk, wv, wo, w1, w2, mask_w};
    int n8s[9] = {393216, 131072, 131072, 131072, 131072, 131072, 524288, 524288, 524288};
    int c = 0;
    for (int i = 0; i < 9; i++) { cs.src[i] = srcs[i]; cs.cum[i] = c; c += n8s[i]; }
    cs.cum[9] = c;  // 2621440
    cast_multi_kernel<<<dim3((c + 255) / 256), dim3(256), 0, stream>>>(cs, bf(0));
  }

  // ---- self attention ----
  ln_bf16_kernel<<<2048, 256, 0, stream>>>(query, ln1_g, ln1_b, bf(OF_QN));

  // qkv = qn @ sa_in_w^T + b  -> bf16 [2048 x 3072]
  launch_gemm<128, false, true, 0, false, false, true>(stream, 2048, 3072, 1024, 1, 1,
      bf(OF_QN), 0, 1024, 0, 0, bf(WB_SAIN), 0, 1024, 0, 0, sa_in_b, nullptr,
      ZF, 0, 0, 0, 0, bf(OF_QKV), 0, 3072, 0, 0);

  // self scores [b,h][256][256] fp32; z=(b*8+h)
  launch_gemm<128, false, false, 0, false, true, false>(stream, 256, 256, 128, 64, 8,
      bf(OF_QKV), 0, 24576, 3072, 128,
      bf(OF_QKV), 1024, 24576, 3072, 128, nullptr, nullptr,
      fp(OF_SC), 0, 256, 524288, 65536, ZB, 0, 0, 0, 0);

  softmax_bf16_kernel<false, 1><<<16384, 256, 0, stream>>>(
      fp(OF_SC), nullptr, bf(OF_P), 0.08838834764831845f);

  // self V^T: VT_s[z=(b*8+h)][d=128][s=256]
  transpose_bf16_kernel<<<dim3(4, 8, 64), 256, 0, stream>>>(
      bf(OF_QKV), bf(OF_QN), 2048L, 24576, 3072L, 128L, 8, 0L, 256, 262144L, 32768L);

  // ctx = attn_p @ VT_s^T  (TM=64 -> 256 blocks)
  launch_gemm<64, false, false, 0, false, false, true>(stream, 256, 128, 256, 64, 8,
      bf(OF_P), 0, 256, 524288, 65536,
      bf(OF_QN), 0, 256, 262144, 32768, nullptr, nullptr,
      ZF, 0, 0, 0, 0, bf(OF_CTX), 0, 8192, 1024, 128);

  // x1 = query + ctx @ sa_out_w^T + b -> fp32 at OF_QKV (TM=64)
  launch_gemm<64, false, true, 0, true, true, false>(stream, 2048, 1024, 1024, 1, 1,
      bf(OF_CTX), 0, 1024, 0, 0, bf(WB_SAOUT), 0, 1024, 0, 0, sa_out_b, query,
      fp(OF_QKV), 0, 1024, 0, 0, ZB, 0, 0, 0, 0);

  // ---- cross attention ----
  ln_bf16_kernel<<<2048, 256, 0, stream>>>(fp(OF_QKV), ln2_g, ln2_b, bf(OF_QN));

  launch_gemm<64, false, true, 0, false, false, true>(stream, 2048, 1024, 1024, 1, 1,
      bf(OF_QN), 0, 1024, 0, 0, bf(WB_WQ), 0, 1024, 0, 0, bq, nullptr,
      ZF, 0, 0, 0, 0, bf(OF_Q), 0, 1024, 0, 0);

  // fused K,V projection: [32768 x 2048] vs wk||wv, planar outputs K@OF_K, V@OF_V
  bias_concat_kernel<<<8, 256, 0, stream>>>(bk, bv, fp(OF_BKV));
  if (fast) {
    cast_bf16_kernel<<<16384, 256, 0, stream>>>(memoryp, bf(OF_MEMBF), 4194304);
    launch_gemm<128, false, true, 0, false, false, true, true>(stream, 32768, 2048, 1024, 1, 1,
        bf(OF_MEMBF), 0, 1024, 0, 0, bf(WB_WK), 0, 1024, 0, 0, fp(OF_BKV), nullptr,
        ZF, 0, 0, 0, 0, bf(OF_K), 0, 1024, 33554432, 0);
  } else {
    launch_gemm<128, true, true, 0, false, false, true, true>(stream, 32768, 2048, 1024, 1, 1,
        memoryp, 0, 1024, 0, 0, bf(WB_WK), 0, 1024, 0, 0, fp(OF_BKV), nullptr,
        ZF, 0, 0, 0, 0, bf(OF_K), 0, 1024, 33554432, 0);
  }

  // cross scores [b][256][4096] fp32
  launch_gemm<128, false, false, 0, false, true, false>(stream, 256, 4096, 1024, 8, 1,
      bf(OF_Q), 0, 8192, 1024, 0,
      bf(OF_K), 0, 8192, 1024, 0, nullptr, nullptr,
      fp(OF_SC), 0, 4096, 1048576, 0, ZB, 0, 0, 0, 0);

  softmax_bf16_kernel<true, 16><<<2048, 256, 0, stream>>>(
      fp(OF_SC), prev_mask, bf(OF_P), 0.03125f);

  // V^T[b][d=1024][s=4096] into OF_K region (K dead now)
  transpose_bf16_kernel<<<dim3(32, 128, 8), 256, 0, stream>>>(
      bf(OF_V), bf(OF_K), 0L, 8192, 1024L, 0L, 1, 0L, 4096, 4194304L, 0L);

  // ctx2 = attn2 @ VT^T (TM=64 -> 256 blocks)
  launch_gemm<64, false, false, 0, false, false, true>(stream, 256, 1024, 4096, 8, 1,
      bf(OF_P), 0, 4096, 1048576, 0,
      bf(OF_K), 0, 4096, 4194304, 0, nullptr, nullptr,
      ZF, 0, 0, 0, 0, bf(OF_CTX), 0, 8192, 1024, 0);

  // x2 = x1 + ctx2 @ wo^T + bo -> fp32 at OF_SC (TM=64)
  launch_gemm<64, false, true, 0, true, true, false>(stream, 2048, 1024, 1024, 1, 1,
      bf(OF_CTX), 0, 1024, 0, 0, bf(WB_WO), 0, 1024, 0, 0, bo, fp(OF_QKV),
      fp(OF_SC), 0, 1024, 0, 0, ZB, 0, 0, 0, 0);

  // ---- FFN ----
  ln_bf16_kernel<<<2048, 256, 0, stream>>>(fp(OF_SC), ln3_g, ln3_b, bf(OF_QN));

  // h = gelu(qn3 @ w1^T + b1) -> bf16 [2048 x 4096]
  launch_gemm<128, false, true, 1, false, false, true>(stream, 2048, 4096, 1024, 1, 1,
      bf(OF_QN), 0, 1024, 0, 0, bf(WB_W1), 0, 1024, 0, 0, b1, nullptr,
      ZF, 0, 0, 0, 0, bf(OF_P), 0, 4096, 0, 0);

  // x3 = x2 + h @ w2^T + b2 -> d_out (fp32) and bf16 copy (TM=64)
  launch_gemm<64, false, true, 0, true, true, true>(stream, 2048, 1024, 4096, 1, 1,
      bf(OF_P), 0, 4096, 0, 0, bf(WB_W2), 0, 4096, 0, 0, b2, fp(OF_SC),
      (float*)d_out, 0, 1024, 0, 0, bf(OF_CTX), 0, 1024, 0, 0);

  // pred_mask[b][q][4096] = sigmoid(x3 @ mask_w^T + mask_b)
  launch_gemm<128, false, true, 2, false, true, false>(stream, 256, 4096, 1024, 8, 1,
      bf(OF_CTX), 0, 8192, 1024, 0,
      bf(WB_MW), 0, 1024, 0, 0, mask_b, nullptr,
      (float*)d_out + 2097152, 0, 4096, 1048576, 0, ZB, 0, 0, 0, 0);
}

// Round 3
// 1004.065 us; speedup vs baseline: 1.1187x; 1.0297x over previous
//
#include <hip/hip_runtime.h>
#include <cstdint>

// ---------------------------------------------------------------------------
// MaskedTransformerDecoderLayer on MI355X.
// All GEMMs: bf16-MFMA tiles (16x16x32), fp32 accumulate, double-buffered LDS.
// D=1024, NHEAD=8, NQ=256, B=8, S=4096, FF=4096.
// ---------------------------------------------------------------------------

typedef __attribute__((ext_vector_type(8))) __bf16 bf16x8;
typedef __attribute__((ext_vector_type(4))) float f32x4;
typedef __attribute__((ext_vector_type(8))) unsigned short ushort8;
typedef __attribute__((ext_vector_type(4))) unsigned short ushort4v;

__device__ __forceinline__ unsigned short f2bf(float f) {
  return __builtin_bit_cast(unsigned short, (__bf16)f);
}

// ---------------- cast fp32 -> bf16 (8 elems/thread) ----------------
__global__ __launch_bounds__(256) void cast_bf16_kernel(const float* __restrict__ in,
                                                        unsigned short* __restrict__ out,
                                                        int n8) {
  int i = blockIdx.x * 256 + threadIdx.x;
  if (i >= n8) return;
  const float4* p = (const float4*)in + (size_t)i * 2;
  float4 a = p[0], b = p[1];
  ushort8 o;
  o[0] = f2bf(a.x); o[1] = f2bf(a.y); o[2] = f2bf(a.z); o[3] = f2bf(a.w);
  o[4] = f2bf(b.x); o[5] = f2bf(b.y); o[6] = f2bf(b.z); o[7] = f2bf(b.w);
  ((ushort8*)out)[i] = o;
}

// ---------------- fused multi-tensor cast (dst regions contiguous) ----------
struct CastSegs {
  const float* src[9];
  int cum[10];  // cumulative n8 counts
};
__global__ __launch_bounds__(256) void cast_multi_kernel(CastSegs cs,
                                                         unsigned short* __restrict__ out) {
  int i = blockIdx.x * 256 + threadIdx.x;
  if (i >= cs.cum[9]) return;
  int s = 0;
  while (i >= cs.cum[s + 1]) s++;
  const float4* p = (const float4*)cs.src[s] + (size_t)(i - cs.cum[s]) * 2;
  float4 a = p[0], b = p[1];
  ushort8 o;
  o[0] = f2bf(a.x); o[1] = f2bf(a.y); o[2] = f2bf(a.z); o[3] = f2bf(a.w);
  o[4] = f2bf(b.x); o[5] = f2bf(b.y); o[6] = f2bf(b.z); o[7] = f2bf(b.w);
  ((ushort8*)out)[i] = o;
}

__global__ __launch_bounds__(256) void bias_concat_kernel(const float* __restrict__ a,
                                                          const float* __restrict__ b,
                                                          float* __restrict__ o) {
  int i = blockIdx.x * 256 + threadIdx.x;
  o[i] = i < 1024 ? a[i] : b[i - 1024];
}

// ---------------- LayerNorm over D=1024, bf16 out ----------------
__global__ __launch_bounds__(256) void ln_bf16_kernel(const float* __restrict__ x,
                                                      const float* __restrict__ g,
                                                      const float* __restrict__ b,
                                                      unsigned short* __restrict__ out) {
  int row = blockIdx.x, tid = threadIdx.x;
  const float4* xr = (const float4*)(x + (size_t)row * 1024);
  float4 v = xr[tid];
  float s = v.x + v.y + v.z + v.w;
  float sq = v.x * v.x + v.y * v.y + v.z * v.z + v.w * v.w;
#pragma unroll
  for (int o = 32; o > 0; o >>= 1) { s += __shfl_xor(s, o); sq += __shfl_xor(sq, o); }
  __shared__ float red[8];
  int wave = tid >> 6, lane = tid & 63;
  if (lane == 0) { red[wave] = s; red[4 + wave] = sq; }
  __syncthreads();
  float ts = red[0] + red[1] + red[2] + red[3];
  float tq = red[4] + red[5] + red[6] + red[7];
  float mean = ts * (1.f / 1024.f);
  float var = tq * (1.f / 1024.f) - mean * mean;
  float rstd = rsqrtf(var + 1e-5f);
  float4 gv = ((const float4*)g)[tid];
  float4 bv = ((const float4*)b)[tid];
  ushort4v o;
  o[0] = f2bf((v.x - mean) * rstd * gv.x + bv.x);
  o[1] = f2bf((v.y - mean) * rstd * gv.y + bv.y);
  o[2] = f2bf((v.z - mean) * rstd * gv.z + bv.z);
  o[3] = f2bf((v.w - mean) * rstd * gv.w + bv.w);
  ((ushort4v*)(out + (size_t)row * 1024))[tid] = o;
}

// ---------------- rowwise softmax, optional +log(mask+1e-6), bf16 out -------
template <bool MASK, int CNT>
__global__ __launch_bounds__(256) void softmax_bf16_kernel(const float* __restrict__ sc,
                                                           const float* __restrict__ pm,
                                                           unsigned short* __restrict__ out,
                                                           float scale) {
  const int L = CNT * 256;
  int row = blockIdx.x, tid = threadIdx.x;
  const float* sr = sc + (size_t)row * L;
  float vals[CNT];
  float mx = -1e30f;
#pragma unroll
  for (int i = 0; i < CNT; i++) {
    int idx = tid + (i << 8);
    float v = sr[idx] * scale;
    if (MASK) v += __logf(pm[(size_t)row * L + idx] + 1e-6f);
    vals[i] = v;
    mx = fmaxf(mx, v);
  }
#pragma unroll
  for (int o = 32; o > 0; o >>= 1) mx = fmaxf(mx, __shfl_xor(mx, o));
  __shared__ float red[8];
  int wave = tid >> 6, lane = tid & 63;
  if (lane == 0) red[wave] = mx;
  __syncthreads();
  mx = fmaxf(fmaxf(red[0], red[1]), fmaxf(red[2], red[3]));
  float sum = 0.f;
#pragma unroll
  for (int i = 0; i < CNT; i++) { vals[i] = __expf(vals[i] - mx); sum += vals[i]; }
#pragma unroll
  for (int o = 32; o > 0; o >>= 1) sum += __shfl_xor(sum, o);
  if (lane == 0) red[4 + wave] = sum;
  __syncthreads();
  float rs = 1.f / (red[4] + red[5] + red[6] + red[7]);
#pragma unroll
  for (int i = 0; i < CNT; i++)
    out[(size_t)row * L + tid + (i << 8)] = f2bf(vals[i] * rs);
}

// ---------------- batched bf16 transpose (32x32 tiles via LDS) ----------------
__global__ __launch_bounds__(256) void transpose_bf16_kernel(
    const unsigned short* __restrict__ in, unsigned short* __restrict__ out,
    long in_off, int in_rs, long in_hi, long in_lo, int zdiv,
    long out_off, int out_rs, long out_hi, long out_lo) {
  __shared__ unsigned short t[32][33];
  int z = blockIdx.z;
  int zh = z / zdiv, zl = z % zdiv;
  const unsigned short* ib = in + in_off + (long)zh * in_hi + (long)zl * in_lo;
  unsigned short* ob = out + out_off + (long)zh * out_hi + (long)zl * out_lo;
  int i0 = blockIdx.x * 32;
  int j0 = blockIdx.y * 32;
  int tx = threadIdx.x & 31, ty = threadIdx.x >> 5;
#pragma unroll
  for (int r = ty; r < 32; r += 8) t[r][tx] = ib[(long)(j0 + r) * in_rs + i0 + tx];
  __syncthreads();
#pragma unroll
  for (int r = ty; r < 32; r += 8) ob[(long)(i0 + r) * out_rs + j0 + tx] = t[tx][r];
}

// ---------------- batched NT GEMM: C[m,n] = sum_k A[m,k]*B[n,k] ----------------
// Tile TM x 128, BK=32, 4 waves (2x2), DOUBLE-BUFFERED LDS: tile k+1 is staged
// before the MFMA phase of tile k, so the vmcnt(0) drain at the next barrier
// overlaps a full compute phase (critical for 1-block/CU small-grid GEMMs).
// AF32: A fp32, converted during staging (TM=128 only). KVSPLIT: bf16 cols
// [0,1024)->plane 0, [1024,2048)->plane 1 at +cb_hi (planar K/V).
template <int TM, bool AF32, bool BIAS, int ACT, bool RES, bool OUTF, bool OUTB, bool KVSPLIT>
__global__ __launch_bounds__(256) void gemm_nt_kernel(
    const void* __restrict__ Av, long a_off, int lda, long a_hi, long a_lo,
    const unsigned short* __restrict__ B, long b_off, int ldb, long b_hi, long b_lo,
    const float* __restrict__ bias, const float* __restrict__ Res,
    float* __restrict__ Cf, long c_off, int ldc, long c_hi, long c_lo,
    unsigned short* __restrict__ Cb, long cb_off, int ldcb, long cb_hi, long cb_lo,
    int K, int zdiv) {
  constexpr int MI = TM / 32;
  __shared__ unsigned short As[2 * TM * 32];
  __shared__ unsigned short Bs[2 * 128 * 32];
  int tid = threadIdx.x;
  int wave = tid >> 6, lane = tid & 63;
  int z = blockIdx.z, zh = z / zdiv, zl = z % zdiv;
  long m0 = (long)blockIdx.x * TM, n0 = (long)blockIdx.y * 128;

  const unsigned short* Bb = B + b_off + zh * b_hi + zl * b_lo + n0 * ldb;
  const unsigned short* Ab16 = nullptr;
  const float* Abf = nullptr;
  if constexpr (AF32)
    Abf = (const float*)Av + a_off + zh * a_hi + zl * a_lo + m0 * lda;
  else
    Ab16 = (const unsigned short*)Av + a_off + zh * a_hi + zl * a_lo + m0 * lda;

  int srow = lane >> 2;
  int scol = (lane & 3) * 8;
  int wm = (wave >> 1) * (TM / 2), wn = (wave & 1) * 64;
  int fr = lane & 15;
  int ko = (lane >> 4) * 8;

  f32x4 acc[MI][4] = {};

  auto stage = [&](int buf, int k0) {
    unsigned short* Ad = As + buf * (TM * 32);
    unsigned short* Bd = Bs + buf * (128 * 32);
    if constexpr (AF32) {
      int row = tid >> 1;
      int cs = (tid & 1) * 16;
      const float* ap = Abf + (long)row * lda + k0 + cs;
      float4 f0 = ((const float4*)ap)[0];
      float4 f1 = ((const float4*)ap)[1];
      float4 f2 = ((const float4*)ap)[2];
      float4 f3 = ((const float4*)ap)[3];
      ushort8 u0, u1;
      u0[0] = f2bf(f0.x); u0[1] = f2bf(f0.y); u0[2] = f2bf(f0.z); u0[3] = f2bf(f0.w);
      u0[4] = f2bf(f1.x); u0[5] = f2bf(f1.y); u0[6] = f2bf(f1.z); u0[7] = f2bf(f1.w);
      u1[0] = f2bf(f2.x); u1[1] = f2bf(f2.y); u1[2] = f2bf(f2.z); u1[3] = f2bf(f2.w);
      u1[4] = f2bf(f3.x); u1[5] = f2bf(f3.y); u1[6] = f2bf(f3.z); u1[7] = f2bf(f3.w);
      ushort8* dst = (ushort8*)(Ad + row * 32 + cs);
      dst[0] = u0;
      dst[1] = u1;
    } else {
#pragma unroll
      for (int is = 0; is < TM / 64; is++) {
        int rbase = wave * (TM / 4) + is * 16;
        const unsigned short* g = Ab16 + (long)(rbase + srow) * lda + k0 + scol;
        __builtin_amdgcn_global_load_lds(
            (const __attribute__((address_space(1))) unsigned int*)g,
            (__attribute__((address_space(3))) unsigned int*)(Ad + rbase * 32), 16, 0, 0);
      }
    }
#pragma unroll
    for (int is = 0; is < 2; is++) {
      int rbase = wave * 32 + is * 16;
      const unsigned short* g = Bb + (long)(rbase + srow) * ldb + k0 + scol;
      __builtin_amdgcn_global_load_lds(
          (const __attribute__((address_space(1))) unsigned int*)g,
          (__attribute__((address_space(3))) unsigned int*)(Bd + rbase * 32), 16, 0, 0);
    }
  };

  stage(0, 0);
  int cur = 0;
  for (int k0 = 0; k0 < K; k0 += 32, cur ^= 1) {
    __syncthreads();  // drains vmcnt: As/Bs[cur] ready; prev reads of [cur] done
    if (k0 + 32 < K) stage(cur ^ 1, k0 + 32);

    const unsigned short* Ar = As + cur * (TM * 32);
    const unsigned short* Br = Bs + cur * (128 * 32);
    bf16x8 af[MI], bfv[4];
#pragma unroll
    for (int i = 0; i < MI; i++)
      af[i] = *(const bf16x8*)(Ar + (wm + i * 16 + fr) * 32 + ko);
#pragma unroll
    for (int j = 0; j < 4; j++)
      bfv[j] = *(const bf16x8*)(Br + (wn + j * 16 + fr) * 32 + ko);
#pragma unroll
    for (int i = 0; i < MI; i++)
#pragma unroll
      for (int j = 0; j < 4; j++)
        acc[i][j] = __builtin_amdgcn_mfma_f32_16x16x32_bf16(af[i], bfv[j], acc[i][j], 0, 0, 0);
  }

  // epilogue: C/D layout col=lane&15, row=(lane>>4)*4+r
  long cfo = c_off + zh * c_hi + zl * c_lo;
  long cbo = cb_off + zh * cb_hi + zl * cb_lo;
  int rq = (lane >> 4) * 4;
#pragma unroll
  for (int i = 0; i < MI; i++) {
    long rbase = m0 + wm + i * 16 + rq;
#pragma unroll
    for (int j = 0; j < 4; j++) {
      long cc = n0 + wn + j * 16 + fr;
      float bsv = BIAS ? bias[cc] : 0.f;
      long p = KVSPLIT ? ((cc >> 10) * cb_hi + (cc & 1023)) : cc;
#pragma unroll
      for (int r = 0; r < 4; r++) {
        float v = acc[i][j][r] + bsv;
        long ro = rbase + r;
        if constexpr (RES) v += Res[cfo + ro * ldc + cc];
        if constexpr (ACT == 1) v = 0.5f * v * (1.f + erff(v * 0.7071067811865475f));
        if constexpr (ACT == 2) v = 1.f / (1.f + __expf(-v));
        if constexpr (OUTF) Cf[cfo + ro * ldc + cc] = v;
        if constexpr (OUTB) Cb[cbo + ro * ldcb + p] = f2bf(v);
      }
    }
  }
}

// ---------------------------------------------------------------------------
// Host side
// ---------------------------------------------------------------------------
template <int TM, bool AF32, bool BIAS, int ACT, bool RES, bool OUTF, bool OUTB, bool KVSPLIT = false>
static void launch_gemm(hipStream_t s, int M, int N, int K, int nz, int zdiv,
                        const void* A, long a_off, int lda, long a_hi, long a_lo,
                        const unsigned short* B, long b_off, int ldb, long b_hi, long b_lo,
                        const float* bias, const float* Res,
                        float* Cf, long c_off, int ldc, long c_hi, long c_lo,
                        unsigned short* Cb, long cb_off, int ldcb, long cb_hi, long cb_lo) {
  dim3 g(M / TM, N / 128, nz);
  gemm_nt_kernel<TM, AF32, BIAS, ACT, RES, OUTF, OUTB, KVSPLIT><<<g, dim3(256), 0, s>>>(
      A, a_off, lda, a_hi, a_lo, B, b_off, ldb, b_hi, b_lo, bias, Res,
      Cf, c_off, ldc, c_hi, c_lo, Cb, cb_off, ldcb, cb_hi, cb_lo, K, zdiv);
}

// workspace layout (bytes). Weight regions 0..40MiB are CONTIGUOUS in cast order.
static const long WB_SAIN = 0;          // 6 MiB
static const long WB_SAOUT = 6291456;   // 2 MiB
static const long WB_WQ = 8388608;      // 2 MiB
static const long WB_WK = 10485760;     // 2 MiB  (wk||wv contiguous -> fused KV B)
static const long WB_WV = 12582912;     // 2 MiB
static const long WB_WO = 14680064;     // 2 MiB
static const long WB_W1 = 16777216;     // 8 MiB
static const long WB_W2 = 25165824;     // 8 MiB
static const long WB_MW = 33554432;     // 8 MiB
static const long OF_K = 41943040;      // 64 MiB: K planar; later V^T
static const long OF_V = 109051904;     // 64 MiB: V planar
static const long OF_QKV = 176160768;   // 12 MiB: qkv bf16; later x1 (fp32, 8 MiB)
static const long OF_BKV = 187695104;   // 8 KiB: concat [bk;bv]
static const long OF_SC = 188743680;    // 32 MiB: self-sc / cross-sc / x2 (fp32)
static const long OF_P = 222298112;     // 16 MiB: attn_p / attn2 / h (bf16)
static const long OF_QN = 239075328;    // 4 MiB: LN outs / self V^T (time-disjoint)
static const long OF_Q = 243269632;     // 4 MiB: Q proj
static const long OF_CTX = 247463936;   // 4 MiB: ctx / ctx2 / x3_bf  (end 251658240)
static const long OF_MEMBF = 251658240; // 64 MiB: memory cast to bf16 (fast path only)
static const size_t FAST_WS = 318767104;

extern "C" void kernel_launch(void* const* d_in, const int* in_sizes, int n_in,
                              void* d_out, int out_size, void* d_ws, size_t ws_size,
                              hipStream_t stream) {
  (void)in_sizes; (void)n_in; (void)out_size;
  const float* query = (const float*)d_in[0];
  const float* memoryp = (const float*)d_in[1];
  const float* prev_mask = (const float*)d_in[2];
  const float* sa_in_w = (const float*)d_in[5];
  const float* sa_in_b = (const float*)d_in[6];
  const float* sa_out_w = (const float*)d_in[7];
  const float* sa_out_b = (const float*)d_in[8];
  const float* ln1_g = (const float*)d_in[9], * ln1_b = (const float*)d_in[10];
  const float* ln2_g = (const float*)d_in[11], * ln2_b = (const float*)d_in[12];
  const float* ln3_g = (const float*)d_in[13], * ln3_b = (const float*)d_in[14];
  const float* wq = (const float*)d_in[15], * bq = (const float*)d_in[16];
  const float* wk = (const float*)d_in[17], * bk = (const float*)d_in[18];
  const float* wv = (const float*)d_in[19], * bv = (const float*)d_in[20];
  const float* wo = (const float*)d_in[21], * bo = (const float*)d_in[22];
  const float* w1 = (const float*)d_in[23], * b1 = (const float*)d_in[24];
  const float* w2 = (const float*)d_in[25], * b2 = (const float*)d_in[26];
  const float* mask_w = (const float*)d_in[27], * mask_b = (const float*)d_in[28];

  uint8_t* ws = (uint8_t*)d_ws;
  auto bf = [&](long off) { return (unsigned short*)(ws + off); };
  auto fp = [&](long off) { return (float*)(ws + off); };
  unsigned short* ZB = nullptr;
  float* ZF = nullptr;
  const bool fast = ws_size >= FAST_WS;

  // ---- all 9 weight casts in one launch (dst = ws[0..40MiB) contiguous) ----
  {
    CastSegs cs;
    const float* srcs[9] = {sa_in_w, sa_out_w, wq, wk, wv, wo, w1, w2, mask_w};
    int n8s[9] = {393216, 131072, 131072, 131072, 131072, 131072, 524288, 524288, 524288};
    int c = 0;
    for (int i = 0; i < 9; i++) { cs.src[i] = srcs[i]; cs.cum[i] = c; c += n8s[i]; }
    cs.cum[9] = c;  // 2621440
    cast_multi_kernel<<<dim3((c + 255) / 256), dim3(256), 0, stream>>>(cs, bf(0));
  }

  // ---- self attention ----
  ln_bf16_kernel<<<2048, 256, 0, stream>>>(query, ln1_g, ln1_b, bf(OF_QN));

  // qkv = qn @ sa_in_w^T + b  -> bf16 [2048 x 3072]
  launch_gemm<128, false, true, 0, false, false, true>(stream, 2048, 3072, 1024, 1, 1,
      bf(OF_QN), 0, 1024, 0, 0, bf(WB_SAIN), 0, 1024, 0, 0, sa_in_b, nullptr,
      ZF, 0, 0, 0, 0, bf(OF_QKV), 0, 3072, 0, 0);

  // self scores [b,h][256][256] fp32; z=(b*8+h)
  launch_gemm<128, false, false, 0, false, true, false>(stream, 256, 256, 128, 64, 8,
      bf(OF_QKV), 0, 24576, 3072, 128,
      bf(OF_QKV), 1024, 24576, 3072, 128, nullptr, nullptr,
      fp(OF_SC), 0, 256, 524288, 65536, ZB, 0, 0, 0, 0);

  softmax_bf16_kernel<false, 1><<<16384, 256, 0, stream>>>(
      fp(OF_SC), nullptr, bf(OF_P), 0.08838834764831845f);

  // self V^T: VT_s[z=(b*8+h)][d=128][s=256]
  transpose_bf16_kernel<<<dim3(4, 8, 64), 256, 0, stream>>>(
      bf(OF_QKV), bf(OF_QN), 2048L, 24576, 3072L, 128L, 8, 0L, 256, 262144L, 32768L);

  // ctx = attn_p @ VT_s^T  (TM=64 -> 256 blocks)
  launch_gemm<64, false, false, 0, false, false, true>(stream, 256, 128, 256, 64, 8,
      bf(OF_P), 0, 256, 524288, 65536,
      bf(OF_QN), 0, 256, 262144, 32768, nullptr, nullptr,
      ZF, 0, 0, 0, 0, bf(OF_CTX), 0, 8192, 1024, 128);

  // x1 = query + ctx @ sa_out_w^T + b -> fp32 at OF_QKV (TM=64)
  launch_gemm<64, false, true, 0, true, true, false>(stream, 2048, 1024, 1024, 1, 1,
      bf(OF_CTX), 0, 1024, 0, 0, bf(WB_SAOUT), 0, 1024, 0, 0, sa_out_b, query,
      fp(OF_QKV), 0, 1024, 0, 0, ZB, 0, 0, 0, 0);

  // ---- cross attention ----
  ln_bf16_kernel<<<2048, 256, 0, stream>>>(fp(OF_QKV), ln2_g, ln2_b, bf(OF_QN));

  launch_gemm<64, false, true, 0, false, false, true>(stream, 2048, 1024, 1024, 1, 1,
      bf(OF_QN), 0, 1024, 0, 0, bf(WB_WQ), 0, 1024, 0, 0, bq, nullptr,
      ZF, 0, 0, 0, 0, bf(OF_Q), 0, 1024, 0, 0);

  // fused K,V projection: [32768 x 2048] vs wk||wv, planar outputs K@OF_K, V@OF_V
  bias_concat_kernel<<<8, 256, 0, stream>>>(bk, bv, fp(OF_BKV));
  if (fast) {
    cast_bf16_kernel<<<16384, 256, 0, stream>>>(memoryp, bf(OF_MEMBF), 4194304);
    launch_gemm<128, false, true, 0, false, false, true, true>(stream, 32768, 2048, 1024, 1, 1,
        bf(OF_MEMBF), 0, 1024, 0, 0, bf(WB_WK), 0, 1024, 0, 0, fp(OF_BKV), nullptr,
        ZF, 0, 0, 0, 0, bf(OF_K), 0, 1024, 33554432, 0);
  } else {
    launch_gemm<128, true, true, 0, false, false, true, true>(stream, 32768, 2048, 1024, 1, 1,
        memoryp, 0, 1024, 0, 0, bf(WB_WK), 0, 1024, 0, 0, fp(OF_BKV), nullptr,
        ZF, 0, 0, 0, 0, bf(OF_K), 0, 1024, 33554432, 0);
  }

  // cross scores [b][256][4096] fp32
  launch_gemm<128, false, false, 0, false, true, false>(stream, 256, 4096, 1024, 8, 1,
      bf(OF_Q), 0, 8192, 1024, 0,
      bf(OF_K), 0, 8192, 1024, 0, nullptr, nullptr,
      fp(OF_SC), 0, 4096, 1048576, 0, ZB, 0, 0, 0, 0);

  softmax_bf16_kernel<true, 16><<<2048, 256, 0, stream>>>(
      fp(OF_SC), prev_mask, bf(OF_P), 0.03125f);

  // V^T[b][d=1024][s=4096] into OF_K region (K dead now)
  transpose_bf16_kernel<<<dim3(32, 128, 8), 256, 0, stream>>>(
      bf(OF_V), bf(OF_K), 0L, 8192, 1024L, 0L, 1, 0L, 4096, 4194304L, 0L);

  // ctx2 = attn2 @ VT^T (TM=64 -> 256 blocks)
  launch_gemm<64, false, false, 0, false, false, true>(stream, 256, 1024, 4096, 8, 1,
      bf(OF_P), 0, 4096, 1048576, 0,
      bf(OF_K), 0, 4096, 4194304, 0, nullptr, nullptr,
      ZF, 0, 0, 0, 0, bf(OF_CTX), 0, 8192, 1024, 0);

  // x2 = x1 + ctx2 @ wo^T + bo -> fp32 at OF_SC (TM=64)
  launch_gemm<64, false, true, 0, true, true, false>(stream, 2048, 1024, 1024, 1, 1,
      bf(OF_CTX), 0, 1024, 0, 0, bf(WB_WO), 0, 1024, 0, 0, bo, fp(OF_QKV),
      fp(OF_SC), 0, 1024, 0, 0, ZB, 0, 0, 0, 0);

  // ---- FFN ----
  ln_bf16_kernel<<<2048, 256, 0, stream>>>(fp(OF_SC), ln3_g, ln3_b, bf(OF_QN));

  // h = gelu(qn3 @ w1^T + b1) -> bf16 [2048 x 4096]
  launch_gemm<128, false, true, 1, false, false, true>(stream, 2048, 4096, 1024, 1, 1,
      bf(OF_QN), 0, 1024, 0, 0, bf(WB_W1), 0, 1024, 0, 0, b1, nullptr,
      ZF, 0, 0, 0, 0, bf(OF_P), 0, 4096, 0, 0);

  // x3 = x2 + h @ w2^T + b2 -> d_out (fp32) and bf16 copy (TM=64)
  launch_gemm<64, false, true, 0, true, true, true>(stream, 2048, 1024, 4096, 1, 1,
      bf(OF_P), 0, 4096, 0, 0, bf(WB_W2), 0, 4096, 0, 0, b2, fp(OF_SC),
      (float*)d_out, 0, 1024, 0, 0, bf(OF_CTX), 0, 1024, 0, 0);

  // pred_mask[b][q][4096] = sigmoid(x3 @ mask_w^T + mask_b)
  launch_gemm<128, false, true, 2, false, true, false>(stream, 256, 4096, 1024, 8, 1,
      bf(OF_CTX), 0, 8192, 1024, 0,
      bf(WB_MW), 0, 1024, 0, 0, mask_b, nullptr,
      (float*)d_out + 2097152, 0, 4096, 1048576, 0, ZB, 0, 0, 0, 0);
}